// Round 8
// baseline (1834.857 us; speedup 1.0000x reference)
//
#include <hip/hip_runtime.h>
#include <math.h>

typedef unsigned short u16;
using f32x4  = __attribute__((ext_vector_type(4))) float;
using bf16x8 = __attribute__((ext_vector_type(8))) short;

__device__ __forceinline__ u16 f2bf(float f){
    unsigned u = __float_as_uint(f);
    u += 0x7fffu + ((u >> 16) & 1u);          // RTN-even
    return (u16)(u >> 16);
}
__device__ __forceinline__ float bf2f(u16 s){
    return __uint_as_float(((unsigned)s) << 16);
}
__device__ __forceinline__ void glds16(const u16* gp, u16* lp){
    __builtin_amdgcn_global_load_lds(
        (const __attribute__((address_space(1))) unsigned int*)gp,
        (__attribute__((address_space(3))) unsigned int*)lp, 16, 0, 0);
}
__device__ __forceinline__ float sigf(float v){ return 1.f / (1.f + __expf(-v)); }
__device__ __forceinline__ float tanhfast(float v){ return 2.f / (1.f + __expf(-2.f*v)) - 1.f; }

#define MFMA3(ACC, AH, AL, BH, BL) \
    ACC = __builtin_amdgcn_mfma_f32_16x16x32_bf16(AH, BH, ACC, 0, 0, 0); \
    ACC = __builtin_amdgcn_mfma_f32_16x16x32_bf16(AH, BL, ACC, 0, 0, 0); \
    ACC = __builtin_amdgcn_mfma_f32_16x16x32_bf16(AL, BH, ACC, 0, 0, 0);

// LDS map (u16 units). Phase A staging [0,45056); Phase B g-planes [0,51200).
#define AH_O   0
#define AL_O   6144
#define B1H_O  12288
#define B1L_O  20480
#define B2H_O  28672
#define B2L_O  36864
#define GH_O   0
#define GL_O   25600
#define GROW   200      // padded k'-stride of g planes (192 real) — 400B: 16B-aligned, 2-way banks

// ============ fused per-step kernel: GEMM1 -> LDS g -> GEMM2 -> gates ============
// grid (4 q-chunks, 64 b), 512 threads (8 waves).
template<int LEAN>
__global__ __launch_bounds__(512, 2)
void step_fused(const u16* __restrict__ tRh, const u16* __restrict__ tRl,   // tA read (parity p)
                const u16* __restrict__ lapTh, const u16* __restrict__ lapTl,
                const u16* __restrict__ Wph, const u16* __restrict__ Wpl,
                u16* __restrict__ gTh, u16* __restrict__ gTl,               // [b][n][96] k0 slots
                u16* __restrict__ tWh, u16* __restrict__ tWl,               // tA write (parity p^1)
                float* __restrict__ cT, const float* __restrict__ bias,
                const float* __restrict__ xsrc, float* __restrict__ odst, int t)
{
    __shared__ __attribute__((aligned(16))) u16 smem[51200];   // 100 KB
    const int tid = threadIdx.x, lane = tid & 63, wave = tid >> 6;
    const int r16 = lane & 15, g = lane >> 4;
    const int b = blockIdx.y, N0 = blockIdx.x * 128;

    // ---------------- Phase A: GEMM1 (M=192 = 2 Laplacians x 96c, N=128, K=512) ----------------
    const int wz = wave >> 2, wm1 = (wave >> 1) & 1, wn1 = wave & 1;

    // 88 glds-instrs/iter, 11 per wave; decode (wave-uniform) tile + per-lane swizzled source
    const u16* sPtr[11]; unsigned sLds[11];
#pragma unroll
    for (int i = 0; i < 11; i++){
        const int q = wave + i*8;
        int ql; const u16* srcb; unsigned lofs; size_t gofs;
        if (q < 12)      { ql = q;      srcb = tRh;   lofs = AH_O  + ql*512;
            int ch = ql*64 + lane, m = ch>>3, gs = (ch&7)^(m&7);
            gofs = ((size_t)b*96 + m)*512 + gs*8; }
        else if (q < 24) { ql = q - 12; srcb = tRl;   lofs = AL_O  + ql*512;
            int ch = ql*64 + lane, m = ch>>3, gs = (ch&7)^(m&7);
            gofs = ((size_t)b*96 + m)*512 + gs*8; }
        else if (q < 40) { ql = q - 24; srcb = lapTh; lofs = B1H_O + ql*512;
            int ch = ql*64 + lane, m = ch>>3, gs = (ch&7)^(m&7);
            gofs = (size_t)(N0 + m)*512 + gs*8; }
        else if (q < 56) { ql = q - 40; srcb = lapTl; lofs = B1L_O + ql*512;
            int ch = ql*64 + lane, m = ch>>3, gs = (ch&7)^(m&7);
            gofs = (size_t)(N0 + m)*512 + gs*8; }
        else if (q < 72) { ql = q - 56; srcb = lapTh; lofs = B2H_O + ql*512;
            int ch = ql*64 + lane, m = ch>>3, gs = (ch&7)^(m&7);
            gofs = 262144 + (size_t)(N0 + m)*512 + gs*8; }
        else             { ql = q - 72; srcb = lapTl; lofs = B2L_O + ql*512;
            int ch = ql*64 + lane, m = ch>>3, gs = (ch&7)^(m&7);
            gofs = 262144 + (size_t)(N0 + m)*512 + gs*8; }
        sPtr[i] = srcb + gofs; sLds[i] = lofs;
    }

    f32x4 acc1[3][4];
#pragma unroll
    for (int i = 0; i < 3; i++)
#pragma unroll
        for (int j = 0; j < 4; j++) acc1[i][j] = (f32x4){0.f, 0.f, 0.f, 0.f};

    const int BH_SEL = wz ? B2H_O : B1H_O;
    const int BL_SEL = wz ? B2L_O : B1L_O;

#pragma unroll 1
    for (int kt = 0; kt < 8; kt++){
#pragma unroll
        for (int i = 0; i < 11; i++)
            glds16(sPtr[i] + kt*64, &smem[sLds[i]]);
        __syncthreads();
#pragma unroll
        for (int s = 0; s < 2; s++){
            bf16x8 fah[3], fal[3], fbh[4], fbl[4];
#pragma unroll
            for (int it = 0; it < 3; it++){
                const int row = wm1*48 + it*16 + r16;
                const int e = row*64 + ((((s<<2)|g)) ^ (row & 7))*8;
                fah[it] = *(const bf16x8*)&smem[AH_O + e];
                fal[it] = *(const bf16x8*)&smem[AL_O + e];
            }
#pragma unroll
            for (int jn = 0; jn < 4; jn++){
                const int row = wn1*64 + jn*16 + r16;
                const int e = row*64 + ((((s<<2)|g)) ^ (row & 7))*8;
                fbh[jn] = *(const bf16x8*)&smem[BH_SEL + e];
                fbl[jn] = *(const bf16x8*)&smem[BL_SEL + e];
            }
#pragma unroll
            for (int it = 0; it < 3; it++)
#pragma unroll
                for (int jn = 0; jn < 4; jn++){ MFMA3(acc1[it][jn], fah[it], fal[it], fbh[jn], fbl[jn]); }
        }
        __syncthreads();
    }

    // epilogue: acc1 -> g planes in LDS (overwrites dead staging; fenced by loop's trailing sync)
#pragma unroll
    for (int it = 0; it < 3; it++){
        const int kp0 = wz*96 + wm1*48 + it*16 + g*4;
#pragma unroll
        for (int jn = 0; jn < 4; jn++){
            const int q = wn1*64 + jn*16 + r16;
            const f32x4 v = acc1[it][jn];
            float vv[4] = {v.x, v.y, v.z, v.w};
            u16 hh[4], hl[4];
#pragma unroll
            for (int r = 0; r < 4; r++){ hh[r] = f2bf(vv[r]); hl[r] = f2bf(vv[r] - bf2f(hh[r])); }
            *(ushort4*)&smem[GH_O + q*GROW + kp0] = make_ushort4(hh[0], hh[1], hh[2], hh[3]);
            *(ushort4*)&smem[GL_O + q*GROW + kp0] = make_ushort4(hl[0], hl[1], hl[2], hl[3]);
        }
    }
    __syncthreads();

    // ---------------- Phase B: GEMM2 (M=256, N=128, K=288) + gates ----------------
    const int wm2 = wave >> 1, wn2 = wave & 1;
    f32x4 acc2[4][4];
#pragma unroll
    for (int i = 0; i < 4; i++)
#pragma unroll
        for (int j = 0; j < 4; j++) acc2[i][j] = (f32x4){0.f, 0.f, 0.f, 0.f};

    // sub-K 0..2: B from global gT k0-slots (x/h of this step, written last dispatch)
#pragma unroll 1
    for (int sub = 0; sub < 3; sub++){
        bf16x8 fah[4], fal[4], fbh[4], fbl[4];
#pragma unroll
        for (int ig = 0; ig < 4; ig++){
            const unsigned ao = (unsigned)((ig*64 + wm2*16 + r16)*320 + sub*32 + g*8);
            fah[ig] = *(const bf16x8*)&Wph[ao];
            fal[ig] = *(const bf16x8*)&Wpl[ao];
        }
#pragma unroll
        for (int jn = 0; jn < 4; jn++){
            const size_t bo = ((size_t)b*512 + N0 + wn2*64 + jn*16 + r16)*96 + sub*32 + g*8;
            fbh[jn] = *(const bf16x8*)&gTh[bo];
            fbl[jn] = *(const bf16x8*)&gTl[bo];
        }
#pragma unroll
        for (int ig = 0; ig < 4; ig++)
#pragma unroll
            for (int jn = 0; jn < 4; jn++){ MFMA3(acc2[ig][jn], fah[ig], fal[ig], fbh[jn], fbl[jn]); }
    }
    __syncthreads();   // all k0 gT reads done before any wave's gates/x overwrite gT

    // sub-K 3..8: B from LDS g (no staging, no barriers)
#pragma unroll 1
    for (int sub = 3; sub < 9; sub++){
        bf16x8 fah[4], fal[4], fbh[4], fbl[4];
#pragma unroll
        for (int ig = 0; ig < 4; ig++){
            const unsigned ao = (unsigned)((ig*64 + wm2*16 + r16)*320 + sub*32 + g*8);
            fah[ig] = *(const bf16x8*)&Wph[ao];
            fal[ig] = *(const bf16x8*)&Wpl[ao];
        }
#pragma unroll
        for (int jn = 0; jn < 4; jn++){
            const int e = (wn2*64 + jn*16 + r16)*GROW + (sub - 3)*32 + g*8;
            fbh[jn] = *(const bf16x8*)&smem[GH_O + e];
            fbl[jn] = *(const bf16x8*)&smem[GL_O + e];
        }
#pragma unroll
        for (int ig = 0; ig < 4; ig++)
#pragma unroll
            for (int jn = 0; jn < 4; jn++){ MFMA3(acc2[ig][jn], fah[ig], fal[ig], fbh[jn], fbl[jn]); }
    }

    // gates fully in-register: wave owns u-rows [wm2*16, wm2*16+16) of all 4 gate quadrants
    float bi[4][4];
#pragma unroll
    for (int ig = 0; ig < 4; ig++)
        *(float4*)&bi[ig][0] = *(const float4*)&bias[ig*64 + wm2*16 + g*4];

#pragma unroll
    for (int jn = 0; jn < 4; jn++){
        const int n = N0 + wn2*64 + jn*16 + r16;
        const size_t gtrow = ((size_t)b*512 + n)*96;
        u16 hh[4], hl[4];
#pragma unroll
        for (int r = 0; r < 4; r++){
            const int u = wm2*16 + g*4 + r;
            const float iv = acc2[0][jn][r] + bi[0][r];
            const float jv = acc2[1][jn][r] + bi[1][r];
            const float fv = acc2[2][jn][r] + bi[2][r];
            const float ov = acc2[3][jn][r] + bi[3][r];
            const size_t ci = ((size_t)b*64 + u)*512 + n;
            const float nc = cT[ci]*sigf(fv) + sigf(iv)*tanhfast(jv);
            const float nh = tanhfast(nc)*sigf(ov);
            cT[ci] = nc;
            hh[r] = f2bf(nh); hl[r] = f2bf(nh - bf2f(hh[r]));
            tWh[((size_t)b*96 + 32 + u)*512 + n] = hh[r];
            tWl[((size_t)b*96 + 32 + u)*512 + n] = hl[r];
            if constexpr (LEAN) odst[ci*24 + t] = nh;
            else                odst[(size_t)t*2097152 + ci] = nh;
        }
        const int u0 = wm2*16 + g*4;
        *(ushort4*)&gTh[gtrow + 32 + u0] = make_ushort4(hh[0], hh[1], hh[2], hh[3]);
        *(ushort4*)&gTl[gtrow + 32 + u0] = make_ushort4(hl[0], hl[1], hl[2], hl[3]);
    }

    // x(t+1) -> gT x-slots + next tA x-rows
    if (t < 23){
        const int cg = tid >> 7, nl = tid & 127;
        const int n = N0 + nl;
        const size_t gtrow = ((size_t)b*512 + n)*96;
        u16 xh[8], xl[8];
#pragma unroll
        for (int j = 0; j < 8; j++){
            const int c = cg*8 + j;
            float xv;
            if constexpr (LEAN) xv = xsrc[(((size_t)b*32 + c)*512 + n)*24 + t + 1];
            else                xv = xsrc[(size_t)(t + 1)*1048576 + ((size_t)b*32 + c)*512 + n];
            xh[j] = f2bf(xv); xl[j] = f2bf(xv - bf2f(xh[j]));
            tWh[((size_t)b*96 + c)*512 + n] = xh[j];
            tWl[((size_t)b*96 + c)*512 + n] = xl[j];
        }
        *(ushort4*)&gTh[gtrow + cg*8]     = make_ushort4(xh[0], xh[1], xh[2], xh[3]);
        *(ushort4*)&gTh[gtrow + cg*8 + 4] = make_ushort4(xh[4], xh[5], xh[6], xh[7]);
        *(ushort4*)&gTl[gtrow + cg*8]     = make_ushort4(xl[0], xl[1], xl[2], xl[3]);
        *(ushort4*)&gTl[gtrow + cg*8 + 4] = make_ushort4(xl[4], xl[5], xl[6], xl[7]);
    }
}

// ===================== setup kernels =====================
__global__ void transpose_x_k(const float* __restrict__ x, float* __restrict__ xF)
{
    const int tid = blockIdx.x*256 + threadIdx.x;
    float xv[24];
    const float4* xp = (const float4*)(x + (size_t)tid*24);
#pragma unroll
    for (int j = 0; j < 6; j++) *(float4*)&xv[j*4] = xp[j];
#pragma unroll
    for (int t = 0; t < 24; t++) xF[(size_t)t*1048576 + tid] = xv[t];
}

__global__ void conv_lap1_k(const float* __restrict__ sup, u16* __restrict__ lh, u16* __restrict__ ll)
{
    const int i = blockIdx.x*256 + threadIdx.x;
    const float v = sup[i];
    const u16 h = f2bf(v);
    lh[i] = h; ll[i] = f2bf(v - bf2f(h));
}

__global__ void lap2_k(const float* __restrict__ sup, u16* __restrict__ l2h, u16* __restrict__ l2l)
{
    __shared__ float As[16][17], Bs[16][17];
    const int tx = threadIdx.x & 15, ty = threadIdx.x >> 4;
    const int i0 = blockIdx.y*16, j0 = blockIdx.x*16;
    float acc = 0.f;
    for (int kt = 0; kt < 32; kt++){
        As[ty][tx] = sup[(i0 + ty)*512 + kt*16 + tx];
        Bs[ty][tx] = sup[(kt*16 + ty)*512 + j0 + tx];
        __syncthreads();
#pragma unroll
        for (int k = 0; k < 16; k++) acc = fmaf(As[ty][k], Bs[k][tx], acc);
        __syncthreads();
    }
    const int i = i0 + ty, j = j0 + tx;
    const float v = 2.f*acc - ((i == j) ? 1.f : 0.f);
    const u16 h = f2bf(v);
    l2h[i*512 + j] = h; l2l[i*512 + j] = f2bf(v - bf2f(h));
}

__global__ void conv_w_k(const float* __restrict__ W, u16* __restrict__ wh, u16* __restrict__ wl)
{
    const int idx = blockIdx.x*256 + threadIdx.x;   // 256*320
    const int m = idx / 320, c = idx - m*320;
    float v = 0.f;
    if (c < 96)       v = W[m*288 + 3*c];
    else if (c < 192) v = W[m*288 + 3*(c - 96) + 1];
    else if (c < 288) v = W[m*288 + 3*(c - 192) + 2];
    const u16 h = f2bf(v);
    wh[idx] = h; wl[idx] = f2bf(v - bf2f(h));
}

template<int LEAN>
__global__ void init_k(float* __restrict__ cT,
                       u16* __restrict__ tAh, u16* __restrict__ tAl,
                       u16* __restrict__ gTh, u16* __restrict__ gTl,
                       const float* __restrict__ xsrc)
{
    const int idx = blockIdx.x*256 + threadIdx.x;   // 2,097,152 = (b,u,n)
    const int n = idx & 511, u = (idx >> 9) & 63, b = idx >> 15;
    cT[idx] = 0.f;
    tAh[((size_t)b*96 + 32 + u)*512 + n] = 0;
    tAl[((size_t)b*96 + 32 + u)*512 + n] = 0;
    gTh[((size_t)b*512 + n)*96 + 32 + u] = 0;
    gTl[((size_t)b*512 + n)*96 + 32 + u] = 0;
    if (u < 32){
        const int c = u;
        float xv;
        if constexpr (LEAN) xv = xsrc[(((size_t)b*32 + c)*512 + n)*24];
        else                xv = xsrc[((size_t)b*32 + c)*512 + n];
        const u16 xh = f2bf(xv), xl = f2bf(xv - bf2f(xh));
        tAh[((size_t)b*96 + c)*512 + n] = xh;
        tAl[((size_t)b*96 + c)*512 + n] = xl;
        gTh[((size_t)b*512 + n)*96 + c] = xh;
        gTl[((size_t)b*512 + n)*96 + c] = xl;
    }
}

__global__ void write_out_k(const float* __restrict__ hseq, float* __restrict__ out)
{
    __shared__ float tile[24][513];
    const int bu = blockIdx.x;
    const int tid = threadIdx.x;
    for (int i = tid; i < 24*512; i += 256){
        const int t = i >> 9, q = i & 511;
        tile[t][q] = hseq[(size_t)t*2097152 + (size_t)bu*512 + q];
    }
    __syncthreads();
    float* ob = out + (size_t)bu*(512*24);
    for (int i = tid; i < 512*24; i += 256){
        const int q = i / 24;
        const int t = i - q*24;
        ob[i] = tile[t][q];
    }
}

// ===================== launcher =====================
extern "C" void kernel_launch(void* const* d_in, const int* in_sizes, int n_in,
                              void* d_out, int out_size, void* d_ws, size_t ws_size,
                              hipStream_t stream)
{
    const float* x    = (const float*)d_in[0];
    const float* sup  = (const float*)d_in[1];
    const float* W    = (const float*)d_in[2];
    const float* bias = (const float*)d_in[3];
    float* out = (float*)d_out;

    char* p = (char*)d_ws;
    auto take = [&](size_t bytes) -> char* {
        char* r = p; p += (bytes + 255) & ~(size_t)255; return r;
    };
    u16*   lapTh = (u16*)take((size_t)2*262144*2);
    u16*   lapTl = (u16*)take((size_t)2*262144*2);
    u16*   Wph   = (u16*)take((size_t)256*320*2);
    u16*   Wpl   = (u16*)take((size_t)256*320*2);
    u16*   tAh[2], *tAl[2];
    tAh[0] = (u16*)take((size_t)64*96*512*2);
    tAl[0] = (u16*)take((size_t)64*96*512*2);
    tAh[1] = (u16*)take((size_t)64*96*512*2);
    tAl[1] = (u16*)take((size_t)64*96*512*2);
    u16*   gTh   = (u16*)take((size_t)64*512*96*2);
    u16*   gTl   = (u16*)take((size_t)64*512*96*2);
    float* cT    = (float*)take((size_t)64*64*512*4);
    const size_t fixed_bytes = (size_t)(p - (char*)d_ws);
    const size_t xF_bytes   = (size_t)24*1048576*4;
    const size_t hseq_bytes = (size_t)24*2097152*4;
    const int full = (ws_size >= fixed_bytes + xF_bytes + hseq_bytes + 1024) ? 1 : 0;
    float* xF   = (float*)take(xF_bytes);
    float* hseq = (float*)take(hseq_bytes);

    if (full) transpose_x_k<<<4096, 256, 0, stream>>>(x, xF);
    conv_lap1_k<<<1024, 256, 0, stream>>>(sup, lapTh, lapTl);
    lap2_k<<<dim3(32, 32), 256, 0, stream>>>(sup, lapTh + 262144, lapTl + 262144);
    conv_w_k<<<320, 256, 0, stream>>>(W, Wph, Wpl);
    if (full) init_k<0><<<8192, 256, 0, stream>>>(cT, tAh[0], tAl[0], gTh, gTl, xF);
    else      init_k<1><<<8192, 256, 0, stream>>>(cT, tAh[0], tAl[0], gTh, gTl, x);

    for (int t = 0; t < 24; t++){
        const int pr = t & 1;
        if (full) step_fused<0><<<dim3(4, 64), 512, 0, stream>>>(
            tAh[pr], tAl[pr], lapTh, lapTl, Wph, Wpl, gTh, gTl,
            tAh[pr ^ 1], tAl[pr ^ 1], cT, bias, xF, hseq, t);
        else      step_fused<1><<<dim3(4, 64), 512, 0, stream>>>(
            tAh[pr], tAl[pr], lapTh, lapTl, Wph, Wpl, gTh, gTl,
            tAh[pr ^ 1], tAl[pr ^ 1], cT, bias, x, out, t);
    }
    if (full) write_out_k<<<4096, 256, 0, stream>>>(hseq, out);
}